// Round 1
// baseline (703.378 us; speedup 1.0000x reference)
//
#include <hip/hip_runtime.h>
#include <hip/hip_bf16.h>

#define DEV __device__ __forceinline__

namespace {

constexpr int D     = 1024;
constexpr int F     = 2048;
constexpr int E     = 8;
constexpr int TWO_F = 2 * F;
constexpr int LDA   = 72;   // padded LDS row stride (bf16 elems): 144B -> 4-bank shift/row, 2-way max (free)

typedef short bf16x8 __attribute__((ext_vector_type(8)));
typedef float f32x4  __attribute__((ext_vector_type(4)));

DEV unsigned short f32_to_bf16(float f) {
  unsigned int u = __builtin_bit_cast(unsigned int, f);
  u += 0x7fffu + ((u >> 16) & 1u);   // RNE
  return (unsigned short)(u >> 16);
}

__global__ void zero_f32_kernel(float* __restrict__ p, int n4) {
  int i = blockIdx.x * 256 + threadIdx.x;
  if (i < n4) ((float4*)p)[i] = make_float4(0.f, 0.f, 0.f, 0.f);
}

__global__ void zero_meta_kernel(int* __restrict__ p, int n) {
  if ((int)threadIdx.x < n) p[threadIdx.x] = 0;
}

// n must be a multiple of 8; grid covers exactly n/8 threads (all sizes here are multiples of 2048)
__global__ void cvt_bf16_kernel(const float* __restrict__ src,
                                unsigned short* __restrict__ dst, int n) {
  int i = (blockIdx.x * 256 + threadIdx.x) * 8;
  if (i >= n) return;
  float4 a = *(const float4*)(src + i);
  float4 b = *(const float4*)(src + i + 4);
  uint4 o;
  o.x = (unsigned)f32_to_bf16(a.x) | ((unsigned)f32_to_bf16(a.y) << 16);
  o.y = (unsigned)f32_to_bf16(a.z) | ((unsigned)f32_to_bf16(a.w) << 16);
  o.z = (unsigned)f32_to_bf16(b.x) | ((unsigned)f32_to_bf16(b.y) << 16);
  o.w = (unsigned)f32_to_bf16(b.z) | ((unsigned)f32_to_bf16(b.w) << 16);
  *(uint4*)(dst + i) = o;
}

// Router: one wave (64 lanes) per token; fp32 dot over D=1024, top-2 + softmax.
__global__ void router_kernel(const float* __restrict__ x, const float* __restrict__ Wr,
                              const float* __restrict__ temp,
                              int* __restrict__ topk_idx, float* __restrict__ topk_gate,
                              int* __restrict__ counts, int T) {
  int wid  = blockIdx.x * 4 + (threadIdx.x >> 6);
  int lane = threadIdx.x & 63;
  if (wid >= T) return;
  const float* xr = x + (size_t)wid * D;
  float acc[E];
#pragma unroll
  for (int e = 0; e < E; ++e) acc[e] = 0.f;
  int base = lane * 16;
#pragma unroll
  for (int u = 0; u < 4; ++u) {
    float4 xv = *(const float4*)(xr + base + u * 4);
#pragma unroll
    for (int e = 0; e < E; ++e) {
      float4 wv = *(const float4*)(Wr + e * D + base + u * 4);
      acc[e] += xv.x * wv.x + xv.y * wv.y + xv.z * wv.z + xv.w * wv.w;
    }
  }
#pragma unroll
  for (int e = 0; e < E; ++e) {
    float v = acc[e];
#pragma unroll
    for (int off = 32; off > 0; off >>= 1) v += __shfl_xor(v, off, 64);
    acc[e] = v;
  }
  if (lane == 0) {
    float inv = 1.0f / temp[0];
    float l[E];
#pragma unroll
    for (int e = 0; e < E; ++e) l[e] = acc[e] * inv;
    int e0 = 0;
#pragma unroll
    for (int e = 1; e < E; ++e) if (l[e] > l[e0]) e0 = e;   // first-index tie-break like top_k
    int e1 = (e0 == 0) ? 1 : 0;
#pragma unroll
    for (int e = 0; e < E; ++e) if (e != e0 && l[e] > l[e1]) e1 = e;
    float dlt = l[e1] - l[e0];           // <= 0
    float ed  = __expf(dlt);
    float g0  = 1.f / (1.f + ed);
    float g1  = ed / (1.f + ed);
    topk_idx[2 * wid]      = e0;
    topk_idx[2 * wid + 1]  = e1;
    topk_gate[2 * wid]     = g0;
    topk_gate[2 * wid + 1] = g1;
    atomicAdd(&counts[e0], 1);
    atomicAdd(&counts[e1], 1);
  }
}

__global__ void scan_kernel(const int* __restrict__ counts, int* __restrict__ offsets) {
  if (threadIdx.x == 0) {
    int s = 0;
    for (int e = 0; e < E; ++e) { offsets[e] = s; s += counts[e]; }
  }
}

__global__ void build_kernel(const int* __restrict__ topk_idx, const float* __restrict__ topk_gate,
                             const int* __restrict__ offsets, int* __restrict__ counts2,
                             int* __restrict__ row_token, float* __restrict__ row_gate, int T) {
  int t = blockIdx.x * 256 + threadIdx.x;
  if (t >= T) return;
#pragma unroll
  for (int s = 0; s < 2; ++s) {
    int e = topk_idx[2 * t + s];
    int i = atomicAdd(&counts2[e], 1);
    int g = offsets[e] + i;
    row_token[g] = t;
    row_gate[g]  = topk_gate[2 * t + s];
  }
}

// GEMM1: h = gather(x) @ W1[e]^T for cols [n0,n0+64) and [F+n0,F+n0+64); fused SwiGLU -> a_buf (bf16)
// Block: 256 thr / 4 waves; tile 128 rows x 128 cols (64 h1-cols + 64 h2-cols); BK=64.
__global__ __launch_bounds__(256, 2)
void gemm1_kernel(const unsigned short* __restrict__ xb,
                  const unsigned short* __restrict__ W1b,
                  const float* __restrict__ b1,
                  const int* __restrict__ counts, const int* __restrict__ offsets,
                  const int* __restrict__ row_token,
                  unsigned short* __restrict__ a_buf) {
  const int e  = blockIdx.z;
  const int m0 = blockIdx.y * 128;
  const int n0 = blockIdx.x * 64;
  const int cnt = counts[e];
  if (m0 >= cnt) return;
  const int pairBase = offsets[e];

  __shared__ __align__(16) unsigned short As[128 * LDA];
  __shared__ __align__(16) unsigned short Bs[128 * LDA];
  __shared__ int tokS[128];

  const int tid = threadIdx.x;
  if (tid < 128) {
    int r = m0 + tid;
    tokS[tid] = (r < cnt) ? row_token[pairBase + r] : -1;
  }
  __syncthreads();

  const int lane = tid & 63;
  const int wave = tid >> 6;
  const int quad = lane >> 4;
  const int l16  = lane & 15;
  const int sr   = tid >> 3;   // 0..31 staging row
  const int sc   = tid & 7;    // 0..7  16B chunk

  f32x4 acc[2][8];
#pragma unroll
  for (int i = 0; i < 2; ++i)
#pragma unroll
    for (int j = 0; j < 8; ++j) acc[i][j] = (f32x4){0.f, 0.f, 0.f, 0.f};

  const unsigned short* W1e = W1b + (size_t)e * TWO_F * D;

  for (int k0 = 0; k0 < D; k0 += 64) {
#pragma unroll
    for (int i = 0; i < 4; ++i) {          // A: gathered token rows
      int r = sr + 32 * i;
      int tok = tokS[r];
      uint4 v = make_uint4(0u, 0u, 0u, 0u);
      if (tok >= 0) v = *(const uint4*)(xb + (size_t)tok * D + k0 + sc * 8);
      *(uint4*)(As + r * LDA + sc * 8) = v;
    }
#pragma unroll
    for (int i = 0; i < 4; ++i) {          // B: rows 0-63 = h1 cols, 64-127 = h2 cols
      int r = sr + 32 * i;
      int wrow = (i < 2) ? (n0 + r) : (F + n0 + (r - 64));
      uint4 v = *(const uint4*)(W1e + (size_t)wrow * D + k0 + sc * 8);
      *(uint4*)(Bs + r * LDA + sc * 8) = v;
    }
    __syncthreads();
#pragma unroll
    for (int kk = 0; kk < 64; kk += 32) {
      bf16x8 af[2], bf[8];
#pragma unroll
      for (int i = 0; i < 2; ++i)
        af[i] = *(const bf16x8*)(As + (wave * 32 + i * 16 + l16) * LDA + kk + quad * 8);
#pragma unroll
      for (int j = 0; j < 8; ++j)
        bf[j] = *(const bf16x8*)(Bs + (j * 16 + l16) * LDA + kk + quad * 8);
#pragma unroll
      for (int i = 0; i < 2; ++i)
#pragma unroll
        for (int j = 0; j < 8; ++j)
          acc[i][j] = __builtin_amdgcn_mfma_f32_16x16x32_bf16(af[i], bf[j], acc[i][j], 0, 0, 0);
    }
    __syncthreads();
  }

  // Epilogue: a = h1 * silu(h2); acc[i][j] (cols) pairs with acc[i][j+4] (same lane mapping).
#pragma unroll
  for (int i = 0; i < 2; ++i) {
    int rb = wave * 32 + i * 16 + quad * 4;
#pragma unroll
    for (int j = 0; j < 4; ++j) {
      int col = n0 + j * 16 + l16;
      float bh1 = b1[e * TWO_F + col];
      float bh2 = b1[e * TWO_F + F + col];
#pragma unroll
      for (int rg = 0; rg < 4; ++rg) {
        int r = rb + rg;
        if (m0 + r < cnt) {
          float h1 = acc[i][j][rg] + bh1;
          float h2 = acc[i][j + 4][rg] + bh2;
          float a  = h1 * (h2 / (1.f + __expf(-h2)));
          a_buf[(size_t)(pairBase + m0 + r) * F + col] = f32_to_bf16(a);
        }
      }
    }
  }
}

// GEMM2: y = a @ W2[e]^T ; out[token] += gate * (y + b2)  (fp32 atomics, out pre-zeroed)
__global__ __launch_bounds__(256, 2)
void gemm2_kernel(const unsigned short* __restrict__ a_buf,
                  const unsigned short* __restrict__ W2b,
                  const float* __restrict__ b2,
                  const int* __restrict__ counts, const int* __restrict__ offsets,
                  const int* __restrict__ row_token, const float* __restrict__ row_gate,
                  float* __restrict__ out) {
  const int e  = blockIdx.z;
  const int m0 = blockIdx.y * 128;
  const int n0 = blockIdx.x * 128;
  const int cnt = counts[e];
  if (m0 >= cnt) return;
  const int pairBase = offsets[e];

  __shared__ __align__(16) unsigned short As[128 * LDA];
  __shared__ __align__(16) unsigned short Bs[128 * LDA];
  __shared__ int   tokS[128];
  __shared__ float gateS[128];

  const int tid = threadIdx.x;
  if (tid < 128) {
    int r = m0 + tid;
    bool v = (r < cnt);
    tokS[tid]  = v ? row_token[pairBase + r] : -1;
    gateS[tid] = v ? row_gate[pairBase + r] : 0.f;
  }
  __syncthreads();

  const int lane = tid & 63;
  const int wave = tid >> 6;
  const int quad = lane >> 4;
  const int l16  = lane & 15;
  const int sr   = tid >> 3;
  const int sc   = tid & 7;

  f32x4 acc[2][8];
#pragma unroll
  for (int i = 0; i < 2; ++i)
#pragma unroll
    for (int j = 0; j < 8; ++j) acc[i][j] = (f32x4){0.f, 0.f, 0.f, 0.f};

  const unsigned short* W2e = W2b + (size_t)e * D * F;

  for (int k0 = 0; k0 < F; k0 += 64) {
#pragma unroll
    for (int i = 0; i < 4; ++i) {
      int r = sr + 32 * i;
      uint4 v = make_uint4(0u, 0u, 0u, 0u);
      if (tokS[r] >= 0)
        v = *(const uint4*)(a_buf + (size_t)(pairBase + m0 + r) * F + k0 + sc * 8);
      *(uint4*)(As + r * LDA + sc * 8) = v;
    }
#pragma unroll
    for (int i = 0; i < 4; ++i) {
      int r = sr + 32 * i;
      uint4 v = *(const uint4*)(W2e + (size_t)(n0 + r) * F + k0 + sc * 8);
      *(uint4*)(Bs + r * LDA + sc * 8) = v;
    }
    __syncthreads();
#pragma unroll
    for (int kk = 0; kk < 64; kk += 32) {
      bf16x8 af[2], bf[8];
#pragma unroll
      for (int i = 0; i < 2; ++i)
        af[i] = *(const bf16x8*)(As + (wave * 32 + i * 16 + l16) * LDA + kk + quad * 8);
#pragma unroll
      for (int j = 0; j < 8; ++j)
        bf[j] = *(const bf16x8*)(Bs + (j * 16 + l16) * LDA + kk + quad * 8);
#pragma unroll
      for (int i = 0; i < 2; ++i)
#pragma unroll
        for (int j = 0; j < 8; ++j)
          acc[i][j] = __builtin_amdgcn_mfma_f32_16x16x32_bf16(af[i], bf[j], acc[i][j], 0, 0, 0);
    }
    __syncthreads();
  }

#pragma unroll
  for (int i = 0; i < 2; ++i) {
    int rb = wave * 32 + i * 16 + quad * 4;
#pragma unroll
    for (int j = 0; j < 8; ++j) {
      int col = n0 + j * 16 + l16;
      float b2v = b2[e * D + col];
#pragma unroll
      for (int rg = 0; rg < 4; ++rg) {
        int r = rb + rg;
        if (m0 + r < cnt) {
          float y = (acc[i][j][rg] + b2v) * gateS[r];
          atomicAdd(&out[(size_t)tokS[r] * D + col], y);
        }
      }
    }
  }
}

}  // namespace

extern "C" void kernel_launch(void* const* d_in, const int* in_sizes, int n_in,
                              void* d_out, int out_size, void* d_ws, size_t ws_size,
                              hipStream_t stream) {
  (void)n_in; (void)out_size; (void)ws_size;
  const float* x    = (const float*)d_in[0];
  const float* Wr   = (const float*)d_in[1];
  const float* temp = (const float*)d_in[2];
  const float* W1   = (const float*)d_in[3];
  const float* b1   = (const float*)d_in[4];
  const float* W2   = (const float*)d_in[5];
  const float* b2   = (const float*)d_in[6];
  float* out = (float*)d_out;
  const int T = in_sizes[0] / D;   // 4096

  // workspace layout (needs ~137 MB)
  char* ws = (char*)d_ws;
  size_t off = 0;
  unsigned short* xb    = (unsigned short*)(ws + off); off += (size_t)T * D * 2;          //  8 MB
  unsigned short* W1b   = (unsigned short*)(ws + off); off += (size_t)E * TWO_F * D * 2;  // 64 MB
  unsigned short* W2b   = (unsigned short*)(ws + off); off += (size_t)E * D * F * 2;      // 32 MB
  unsigned short* a_buf = (unsigned short*)(ws + off); off += (size_t)T * 2 * F * 2;      // 32 MB
  int*   counts    = (int*)(ws + off); off += 64;
  int*   offsets   = (int*)(ws + off); off += 64;
  int*   counts2   = (int*)(ws + off); off += 64;
  int*   topk_idx  = (int*)(ws + off); off += (size_t)T * 2 * 4;
  float* topk_gate = (float*)(ws + off); off += (size_t)T * 2 * 4;
  int*   row_token = (int*)(ws + off); off += (size_t)T * 2 * 4;
  float* row_gate  = (float*)(ws + off); off += (size_t)T * 2 * 4;

  zero_f32_kernel<<<(T * D / 4 + 255) / 256, 256, 0, stream>>>(out, T * D / 4);
  zero_meta_kernel<<<1, 64, 0, stream>>>(counts, 48);   // counts+offsets+counts2 are contiguous

  cvt_bf16_kernel<<<T * D / 2048, 256, 0, stream>>>(x, xb, T * D);
  cvt_bf16_kernel<<<E * TWO_F * D / 2048, 256, 0, stream>>>(W1, W1b, E * TWO_F * D);
  cvt_bf16_kernel<<<E * D * F / 2048, 256, 0, stream>>>(W2, W2b, E * D * F);

  router_kernel<<<(T + 3) / 4, 256, 0, stream>>>(x, Wr, temp, topk_idx, topk_gate, counts, T);
  scan_kernel<<<1, 64, 0, stream>>>(counts, offsets);
  build_kernel<<<(T + 255) / 256, 256, 0, stream>>>(topk_idx, topk_gate, offsets, counts2,
                                                    row_token, row_gate, T);

  const int MT = (T + 127) / 128;
  gemm1_kernel<<<dim3(F / 64, MT, E), 256, 0, stream>>>(xb, W1b, b1, counts, offsets,
                                                        row_token, a_buf);
  gemm2_kernel<<<dim3(D / 128, MT, E), 256, 0, stream>>>(a_buf, W2b, b2, counts, offsets,
                                                         row_token, row_gate, out);
}

// Round 2
// 620.869 us; speedup vs baseline: 1.1329x; 1.1329x over previous
//
#include <hip/hip_runtime.h>
#include <hip/hip_bf16.h>

#define DEV __device__ __forceinline__

namespace {

constexpr int D     = 1024;
constexpr int F     = 2048;
constexpr int E     = 8;
constexpr int TWO_F = 2 * F;

typedef short bf16x8 __attribute__((ext_vector_type(8)));
typedef float f32x4  __attribute__((ext_vector_type(4)));

DEV unsigned short f32_to_bf16(float f) {
  unsigned int u = __builtin_bit_cast(unsigned int, f);
  u += 0x7fffu + ((u >> 16) & 1u);   // RNE
  return (unsigned short)(u >> 16);
}

// async global->LDS, 16B per lane; LDS dest must be wave-uniform base (lane*16B implicit)
DEV void load_lds16(const void* g, void* l) {
  __builtin_amdgcn_global_load_lds((const __attribute__((address_space(1))) void*)g,
                                   (__attribute__((address_space(3))) void*)l, 16, 0, 0);
}

// Zero out[] (as float4) and, in block 0, the 48 meta ints (counts/offsets/counts2).
__global__ void zero_kernel(float* __restrict__ p, int n4, int* __restrict__ meta) {
  int i = blockIdx.x * 256 + threadIdx.x;
  if (i < n4) ((float4*)p)[i] = make_float4(0.f, 0.f, 0.f, 0.f);
  if (blockIdx.x == 0 && threadIdx.x < 48) meta[threadIdx.x] = 0;
}

// One fused fp32->bf16 conversion over x, W1, W2 (all sizes multiples of 2048 elems,
// so region selection is block-uniform).
__global__ void cvt_all_kernel(const float* __restrict__ x, const float* __restrict__ W1,
                               const float* __restrict__ W2,
                               unsigned short* __restrict__ xb, unsigned short* __restrict__ W1b,
                               unsigned short* __restrict__ W2b,
                               long long nx, long long n1) {
  long long i = (long long)(blockIdx.x * 256 + threadIdx.x) * 8;
  const float* src;
  unsigned short* dst;
  long long off;
  if (i < nx)            { src = x;  dst = xb;  off = i; }
  else if (i < nx + n1)  { src = W1; dst = W1b; off = i - nx; }
  else                   { src = W2; dst = W2b; off = i - nx - n1; }
  float4 a = *(const float4*)(src + off);
  float4 b = *(const float4*)(src + off + 4);
  uint4 o;
  o.x = (unsigned)f32_to_bf16(a.x) | ((unsigned)f32_to_bf16(a.y) << 16);
  o.y = (unsigned)f32_to_bf16(a.z) | ((unsigned)f32_to_bf16(a.w) << 16);
  o.z = (unsigned)f32_to_bf16(b.x) | ((unsigned)f32_to_bf16(b.y) << 16);
  o.w = (unsigned)f32_to_bf16(b.z) | ((unsigned)f32_to_bf16(b.w) << 16);
  *(uint4*)(dst + off) = o;
}

// Router: one wave (64 lanes) per token; fp32 dot over D=1024, top-2 + softmax.
__global__ void router_kernel(const float* __restrict__ x, const float* __restrict__ Wr,
                              const float* __restrict__ temp,
                              int* __restrict__ topk_idx, float* __restrict__ topk_gate,
                              int* __restrict__ counts, int T) {
  int wid  = blockIdx.x * 4 + (threadIdx.x >> 6);
  int lane = threadIdx.x & 63;
  if (wid >= T) return;
  const float* xr = x + (size_t)wid * D;
  float acc[E];
#pragma unroll
  for (int e = 0; e < E; ++e) acc[e] = 0.f;
  int base = lane * 16;
#pragma unroll
  for (int u = 0; u < 4; ++u) {
    float4 xv = *(const float4*)(xr + base + u * 4);
#pragma unroll
    for (int e = 0; e < E; ++e) {
      float4 wv = *(const float4*)(Wr + e * D + base + u * 4);
      acc[e] += xv.x * wv.x + xv.y * wv.y + xv.z * wv.z + xv.w * wv.w;
    }
  }
#pragma unroll
  for (int e = 0; e < E; ++e) {
    float v = acc[e];
#pragma unroll
    for (int off = 32; off > 0; off >>= 1) v += __shfl_xor(v, off, 64);
    acc[e] = v;
  }
  if (lane == 0) {
    float inv = 1.0f / temp[0];
    float l[E];
#pragma unroll
    for (int e = 0; e < E; ++e) l[e] = acc[e] * inv;
    int e0 = 0;
#pragma unroll
    for (int e = 1; e < E; ++e) if (l[e] > l[e0]) e0 = e;   // first-index tie-break like top_k
    int e1 = (e0 == 0) ? 1 : 0;
#pragma unroll
    for (int e = 0; e < E; ++e) if (e != e0 && l[e] > l[e1]) e1 = e;
    float dlt = l[e1] - l[e0];           // <= 0
    float ed  = __expf(dlt);
    float g0  = 1.f / (1.f + ed);
    float g1  = ed / (1.f + ed);
    topk_idx[2 * wid]      = e0;
    topk_idx[2 * wid + 1]  = e1;
    topk_gate[2 * wid]     = g0;
    topk_gate[2 * wid + 1] = g1;
    atomicAdd(&counts[e0], 1);
    atomicAdd(&counts[e1], 1);
  }
}

__global__ void scan_kernel(const int* __restrict__ counts, int* __restrict__ offsets) {
  if (threadIdx.x == 0) {
    int s = 0;
    for (int e = 0; e < E; ++e) { offsets[e] = s; s += counts[e]; }
  }
}

__global__ void build_kernel(const int* __restrict__ topk_idx, const float* __restrict__ topk_gate,
                             const int* __restrict__ offsets, int* __restrict__ counts2,
                             int* __restrict__ row_token, float* __restrict__ row_gate, int T) {
  int t = blockIdx.x * 256 + threadIdx.x;
  if (t >= T) return;
#pragma unroll
  for (int s = 0; s < 2; ++s) {
    int e = topk_idx[2 * t + s];
    int i = atomicAdd(&counts2[e], 1);
    int g = offsets[e] + i;
    row_token[g] = t;
    row_gate[g]  = topk_gate[2 * t + s];
  }
}

// GEMM1: h = gather(x) @ W1[e]^T for h-cols [n0,n0+64) and [F+n0,F+n0+64); fused SwiGLU -> a_buf
// 256 thr / 4 waves; tile 128 rows x 128 h-cols; BK=64; m97-style global_load_lds staging.
__global__ __launch_bounds__(256, 2)
void gemm1_kernel(const unsigned short* __restrict__ xb,
                  const unsigned short* __restrict__ W1b,
                  const float* __restrict__ b1,
                  const int* __restrict__ counts, const int* __restrict__ offsets,
                  const int* __restrict__ row_token,
                  unsigned short* __restrict__ a_buf) {
  const int e  = blockIdx.z;
  const int m0 = blockIdx.y * 128;
  const int n0 = blockIdx.x * 64;
  const int cnt = counts[e];
  if (m0 >= cnt) return;
  const int pairBase = offsets[e];

  __shared__ __align__(16) unsigned short As[128 * 64];   // unpadded: required by global_load_lds
  __shared__ __align__(16) unsigned short Bs[128 * 64];
  __shared__ int tokS[128];

  const int tid = threadIdx.x;
  if (tid < 128) {
    int r = m0 + tid;
    tokS[tid] = (r < cnt) ? row_token[pairBase + r] : row_token[pairBase];  // clamp: safe garbage
  }
  __syncthreads();

  const int lane = tid & 63;
  const int wave = tid >> 6;
  const int quad = lane >> 4;
  const int l16  = lane & 15;
  const int lr   = lane >> 3;   // 0..7 row within 8-row staging group
  const int lc   = lane & 7;    // 0..7 16B chunk

  const unsigned short* W1e = W1b + (size_t)e * TWO_F * D;
  // hoisted per-lane global pointers (k-invariant)
  const unsigned short* aptr[4];
  const unsigned short* bptr[4];
#pragma unroll
  for (int i = 0; i < 4; ++i) {
    int r = wave * 32 + i * 8 + lr;
    aptr[i] = xb + (size_t)tokS[r] * D + lc * 8;
    int wrow = (r < 64) ? (n0 + r) : (F + n0 + (r - 64));   // rows 0-63: h1 cols, 64-127: h2 cols
    bptr[i] = W1e + (size_t)wrow * D + lc * 8;
  }
  unsigned short* AsW = As + (wave * 32) * 64;
  unsigned short* BsW = Bs + (wave * 32) * 64;

  f32x4 acc[2][8];
#pragma unroll
  for (int i = 0; i < 2; ++i)
#pragma unroll
    for (int j = 0; j < 8; ++j) acc[i][j] = (f32x4){0.f, 0.f, 0.f, 0.f};

  for (int k0 = 0; k0 < D; k0 += 64) {
#pragma unroll
    for (int i = 0; i < 4; ++i) load_lds16(aptr[i] + k0, AsW + i * 8 * 64);
#pragma unroll
    for (int i = 0; i < 4; ++i) load_lds16(bptr[i] + k0, BsW + i * 8 * 64);
    __syncthreads();
#pragma unroll
    for (int kk = 0; kk < 64; kk += 32) {
      bf16x8 af[2], bf[8];
#pragma unroll
      for (int i = 0; i < 2; ++i)
        af[i] = *(const bf16x8*)(As + (wave * 32 + i * 16 + l16) * 64 + kk + quad * 8);
#pragma unroll
      for (int j = 0; j < 8; ++j)
        bf[j] = *(const bf16x8*)(Bs + (j * 16 + l16) * 64 + kk + quad * 8);
#pragma unroll
      for (int i = 0; i < 2; ++i)
#pragma unroll
        for (int j = 0; j < 8; ++j)
          acc[i][j] = __builtin_amdgcn_mfma_f32_16x16x32_bf16(af[i], bf[j], acc[i][j], 0, 0, 0);
    }
    __syncthreads();
  }

  // Epilogue: a = h1 * silu(h2); acc[i][j] pairs with acc[i][j+4] (same lane mapping).
#pragma unroll
  for (int i = 0; i < 2; ++i) {
    int rb = wave * 32 + i * 16 + quad * 4;
#pragma unroll
    for (int j = 0; j < 4; ++j) {
      int col = n0 + j * 16 + l16;
      float bh1 = b1[e * TWO_F + col];
      float bh2 = b1[e * TWO_F + F + col];
#pragma unroll
      for (int rg = 0; rg < 4; ++rg) {
        int r = rb + rg;
        if (m0 + r < cnt) {
          float h1 = acc[i][j][rg] + bh1;
          float h2 = acc[i][j + 4][rg] + bh2;
          float a  = h1 * (h2 / (1.f + __expf(-h2)));
          a_buf[(size_t)(pairBase + m0 + r) * F + col] = f32_to_bf16(a);
        }
      }
    }
  }
}

// GEMM2: y = a @ W2[e]^T ; out[token] += gate * (y + b2)  (fp32 atomics, out pre-zeroed)
// 2x2 wave tiling, 64x64 per wave; m97-style staging.
__global__ __launch_bounds__(256, 2)
void gemm2_kernel(const unsigned short* __restrict__ a_buf,
                  const unsigned short* __restrict__ W2b,
                  const float* __restrict__ b2,
                  const int* __restrict__ counts, const int* __restrict__ offsets,
                  const int* __restrict__ row_token, const float* __restrict__ row_gate,
                  float* __restrict__ out, int totalPairs) {
  const int e  = blockIdx.z;
  const int m0 = blockIdx.y * 128;
  const int n0 = blockIdx.x * 128;
  const int cnt = counts[e];
  if (m0 >= cnt) return;
  const int pairBase = offsets[e];

  __shared__ __align__(16) unsigned short As[128 * 64];
  __shared__ __align__(16) unsigned short Bs[128 * 64];
  __shared__ int   tokS[128];
  __shared__ float gateS[128];

  const int tid = threadIdx.x;
  if (tid < 128) {
    int r = m0 + tid;
    bool v = (r < cnt);
    tokS[tid]  = v ? row_token[pairBase + r] : 0;
    gateS[tid] = v ? row_gate[pairBase + r] : 0.f;
  }
  __syncthreads();

  const int lane = tid & 63;
  const int wave = tid >> 6;
  const int quad = lane >> 4;
  const int l16  = lane & 15;
  const int lr   = lane >> 3;
  const int lc   = lane & 7;
  const int wr   = wave >> 1;    // 0..1 row half
  const int wc   = wave & 1;     // 0..1 col half

  const unsigned short* W2e = W2b + (size_t)e * D * F;
  const unsigned short* aptr[4];
  const unsigned short* bptr[4];
#pragma unroll
  for (int i = 0; i < 4; ++i) {
    int r = wave * 32 + i * 8 + lr;
    int g = pairBase + m0 + r;
    if (g > totalPairs - 1) g = totalPairs - 1;   // clamp: stay inside a_buf
    aptr[i] = a_buf + (size_t)g * F + lc * 8;
    bptr[i] = W2e + (size_t)(n0 + r) * F + lc * 8;
  }
  unsigned short* AsW = As + (wave * 32) * 64;
  unsigned short* BsW = Bs + (wave * 32) * 64;

  f32x4 acc[4][4];
#pragma unroll
  for (int i = 0; i < 4; ++i)
#pragma unroll
    for (int j = 0; j < 4; ++j) acc[i][j] = (f32x4){0.f, 0.f, 0.f, 0.f};

  for (int k0 = 0; k0 < F; k0 += 64) {
#pragma unroll
    for (int i = 0; i < 4; ++i) load_lds16(aptr[i] + k0, AsW + i * 8 * 64);
#pragma unroll
    for (int i = 0; i < 4; ++i) load_lds16(bptr[i] + k0, BsW + i * 8 * 64);
    __syncthreads();
#pragma unroll
    for (int kk = 0; kk < 64; kk += 32) {
      bf16x8 af[4], bf[4];
#pragma unroll
      for (int i = 0; i < 4; ++i)
        af[i] = *(const bf16x8*)(As + (wr * 64 + i * 16 + l16) * 64 + kk + quad * 8);
#pragma unroll
      for (int j = 0; j < 4; ++j)
        bf[j] = *(const bf16x8*)(Bs + (wc * 64 + j * 16 + l16) * 64 + kk + quad * 8);
#pragma unroll
      for (int i = 0; i < 4; ++i)
#pragma unroll
        for (int j = 0; j < 4; ++j)
          acc[i][j] = __builtin_amdgcn_mfma_f32_16x16x32_bf16(af[i], bf[j], acc[i][j], 0, 0, 0);
    }
    __syncthreads();
  }

#pragma unroll
  for (int j = 0; j < 4; ++j) {
    int col = n0 + wc * 64 + j * 16 + l16;
    float b2v = b2[e * D + col];
#pragma unroll
    for (int i = 0; i < 4; ++i) {
      int rb = wr * 64 + i * 16 + quad * 4;
#pragma unroll
      for (int rg = 0; rg < 4; ++rg) {
        int r = rb + rg;
        if (m0 + r < cnt) {
          float y = (acc[i][j][rg] + b2v) * gateS[r];
          atomicAdd(&out[(size_t)tokS[r] * D + col], y);
        }
      }
    }
  }
}

}  // namespace

extern "C" void kernel_launch(void* const* d_in, const int* in_sizes, int n_in,
                              void* d_out, int out_size, void* d_ws, size_t ws_size,
                              hipStream_t stream) {
  (void)n_in; (void)out_size; (void)ws_size;
  const float* x    = (const float*)d_in[0];
  const float* Wr   = (const float*)d_in[1];
  const float* temp = (const float*)d_in[2];
  const float* W1   = (const float*)d_in[3];
  const float* b1   = (const float*)d_in[4];
  const float* W2   = (const float*)d_in[5];
  const float* b2   = (const float*)d_in[6];
  float* out = (float*)d_out;
  const int T = in_sizes[0] / D;   // 4096

  // workspace layout (~137 MB)
  char* ws = (char*)d_ws;
  size_t off = 0;
  unsigned short* xb    = (unsigned short*)(ws + off); off += (size_t)T * D * 2;          //  8 MB
  unsigned short* W1b   = (unsigned short*)(ws + off); off += (size_t)E * TWO_F * D * 2;  // 64 MB
  unsigned short* W2b   = (unsigned short*)(ws + off); off += (size_t)E * D * F * 2;      // 32 MB
  unsigned short* a_buf = (unsigned short*)(ws + off); off += (size_t)T * 2 * F * 2;      // 32 MB
  int*   counts    = (int*)(ws + off); off += 64;
  int*   offsets   = (int*)(ws + off); off += 64;
  int*   counts2   = (int*)(ws + off); off += 64;
  int*   topk_idx  = (int*)(ws + off); off += (size_t)T * 2 * 4;
  float* topk_gate = (float*)(ws + off); off += (size_t)T * 2 * 4;
  int*   row_token = (int*)(ws + off); off += (size_t)T * 2 * 4;
  float* row_gate  = (float*)(ws + off); off += (size_t)T * 2 * 4;

  const long long nx = (long long)T * D;
  const long long n1 = (long long)E * TWO_F * D;
  const long long n2 = (long long)E * D * F;

  zero_kernel<<<(T * D / 4 + 255) / 256, 256, 0, stream>>>(out, T * D / 4, counts);
  cvt_all_kernel<<<(int)((nx + n1 + n2) / 2048), 256, 0, stream>>>(x, W1, W2, xb, W1b, W2b,
                                                                   nx, n1);
  router_kernel<<<(T + 3) / 4, 256, 0, stream>>>(x, Wr, temp, topk_idx, topk_gate, counts, T);
  scan_kernel<<<1, 64, 0, stream>>>(counts, offsets);
  build_kernel<<<(T + 255) / 256, 256, 0, stream>>>(topk_idx, topk_gate, offsets, counts2,
                                                    row_token, row_gate, T);

  const int MT = (T + 127) / 128;
  gemm1_kernel<<<dim3(F / 64, MT, E), 256, 0, stream>>>(xb, W1b, b1, counts, offsets,
                                                        row_token, a_buf);
  gemm2_kernel<<<dim3(D / 128, MT, E), 256, 0, stream>>>(a_buf, W2b, b2, counts, offsets,
                                                         row_token, row_gate, out, T * 2);
}

// Round 3
// 587.975 us; speedup vs baseline: 1.1963x; 1.0559x over previous
//
#include <hip/hip_runtime.h>
#include <hip/hip_bf16.h>

#define DEV __device__ __forceinline__

namespace {

constexpr int D     = 1024;
constexpr int F     = 2048;
constexpr int E     = 8;
constexpr int TWO_F = 2 * F;

typedef short bf16x8 __attribute__((ext_vector_type(8)));
typedef float f32x4  __attribute__((ext_vector_type(4)));

DEV unsigned short f32_to_bf16(float f) {
  unsigned int u = __builtin_bit_cast(unsigned int, f);
  u += 0x7fffu + ((u >> 16) & 1u);   // RNE
  return (unsigned short)(u >> 16);
}

// async global->LDS, 16B per lane; LDS dest is wave-uniform base + lane*16 implicit
DEV void load_lds16(const void* g, void* l) {
  __builtin_amdgcn_global_load_lds((const __attribute__((address_space(1))) void*)g,
                                   (__attribute__((address_space(3))) void*)l, 16, 0, 0);
}

// XOR-swizzled fragment address: LDS[row][c] holds global chunk c ^ (row&7).
// row must satisfy (row&7)==(l16&7) here (row = base8*8 + l16 with base8*8 multiple of 16).
DEV const bf16x8* frag_addr(const unsigned short* S, int row, int kk, int quad) {
  int cl = (((kk >> 3) + quad) ^ (row & 7));
  return (const bf16x8*)(S + row * 64 + cl * 8);
}

// Zero out[] (as float4) and, in block 0, the 48 meta ints (counts/offsets/counts2).
__global__ void zero_kernel(float* __restrict__ p, int n4, int* __restrict__ meta) {
  int i = blockIdx.x * 256 + threadIdx.x;
  if (i < n4) ((float4*)p)[i] = make_float4(0.f, 0.f, 0.f, 0.f);
  if (blockIdx.x == 0 && threadIdx.x < 48) meta[threadIdx.x] = 0;
}

// One fused fp32->bf16 conversion over x, W1, W2 (sizes are multiples of 2048 elems).
__global__ void cvt_all_kernel(const float* __restrict__ x, const float* __restrict__ W1,
                               const float* __restrict__ W2,
                               unsigned short* __restrict__ xb, unsigned short* __restrict__ W1b,
                               unsigned short* __restrict__ W2b,
                               long long nx, long long n1) {
  long long i = (long long)(blockIdx.x * 256 + threadIdx.x) * 8;
  const float* src;
  unsigned short* dst;
  long long off;
  if (i < nx)            { src = x;  dst = xb;  off = i; }
  else if (i < nx + n1)  { src = W1; dst = W1b; off = i - nx; }
  else                   { src = W2; dst = W2b; off = i - nx - n1; }
  float4 a = *(const float4*)(src + off);
  float4 b = *(const float4*)(src + off + 4);
  uint4 o;
  o.x = (unsigned)f32_to_bf16(a.x) | ((unsigned)f32_to_bf16(a.y) << 16);
  o.y = (unsigned)f32_to_bf16(a.z) | ((unsigned)f32_to_bf16(a.w) << 16);
  o.z = (unsigned)f32_to_bf16(b.x) | ((unsigned)f32_to_bf16(b.y) << 16);
  o.w = (unsigned)f32_to_bf16(b.z) | ((unsigned)f32_to_bf16(b.w) << 16);
  *(uint4*)(dst + off) = o;
}

// Router: one wave per token; fp32 dot over D=1024, top-2 + softmax.
__global__ void router_kernel(const float* __restrict__ x, const float* __restrict__ Wr,
                              const float* __restrict__ temp,
                              int* __restrict__ topk_idx, float* __restrict__ topk_gate,
                              int* __restrict__ counts, int T) {
  int wid  = blockIdx.x * 4 + (threadIdx.x >> 6);
  int lane = threadIdx.x & 63;
  if (wid >= T) return;
  const float* xr = x + (size_t)wid * D;
  float acc[E];
#pragma unroll
  for (int e = 0; e < E; ++e) acc[e] = 0.f;
  int base = lane * 16;
#pragma unroll
  for (int u = 0; u < 4; ++u) {
    float4 xv = *(const float4*)(xr + base + u * 4);
#pragma unroll
    for (int e = 0; e < E; ++e) {
      float4 wv = *(const float4*)(Wr + e * D + base + u * 4);
      acc[e] += xv.x * wv.x + xv.y * wv.y + xv.z * wv.z + xv.w * wv.w;
    }
  }
#pragma unroll
  for (int e = 0; e < E; ++e) {
    float v = acc[e];
#pragma unroll
    for (int off = 32; off > 0; off >>= 1) v += __shfl_xor(v, off, 64);
    acc[e] = v;
  }
  if (lane == 0) {
    float inv = 1.0f / temp[0];
    float l[E];
#pragma unroll
    for (int e = 0; e < E; ++e) l[e] = acc[e] * inv;
    int e0 = 0;
#pragma unroll
    for (int e = 1; e < E; ++e) if (l[e] > l[e0]) e0 = e;
    int e1 = (e0 == 0) ? 1 : 0;
#pragma unroll
    for (int e = 0; e < E; ++e) if (e != e0 && l[e] > l[e1]) e1 = e;
    float dlt = l[e1] - l[e0];
    float ed  = __expf(dlt);
    float g0  = 1.f / (1.f + ed);
    float g1  = ed / (1.f + ed);
    topk_idx[2 * wid]      = e0;
    topk_idx[2 * wid + 1]  = e1;
    topk_gate[2 * wid]     = g0;
    topk_gate[2 * wid + 1] = g1;
    atomicAdd(&counts[e0], 1);
    atomicAdd(&counts[e1], 1);
  }
}

__global__ void scan_kernel(const int* __restrict__ counts, int* __restrict__ offsets) {
  if (threadIdx.x == 0) {
    int s = 0;
    for (int e = 0; e < E; ++e) { offsets[e] = s; s += counts[e]; }
  }
}

__global__ void build_kernel(const int* __restrict__ topk_idx, const float* __restrict__ topk_gate,
                             const int* __restrict__ offsets, int* __restrict__ counts2,
                             int* __restrict__ row_token, float* __restrict__ row_gate, int T) {
  int t = blockIdx.x * 256 + threadIdx.x;
  if (t >= T) return;
#pragma unroll
  for (int s = 0; s < 2; ++s) {
    int e = topk_idx[2 * t + s];
    int i = atomicAdd(&counts2[e], 1);
    int g = offsets[e] + i;
    row_token[g] = t;
    row_gate[g]  = topk_gate[2 * t + s];
  }
}

// GEMM1: h = gather(x) @ W1[e]^T; fused SwiGLU -> a_buf (bf16).
// 256 thr / 2x2 waves; tile 128 tokens x 64 a-cols (128 h-cols). BK=64.
// Bs row grouping: [h1 c0..31 | h2 c0..31 | h1 c32..63 | h2 c32..63] so each wave
// owns matching (h1,h2) col pairs: acc[i][j] pairs acc[i][j+2].
__global__ __launch_bounds__(256, 2)
void gemm1_kernel(const unsigned short* __restrict__ xb,
                  const unsigned short* __restrict__ W1b,
                  const float* __restrict__ b1,
                  const int* __restrict__ counts, const int* __restrict__ offsets,
                  const int* __restrict__ row_token,
                  unsigned short* __restrict__ a_buf) {
  const int e  = blockIdx.z;
  const int m0 = blockIdx.y * 128;
  const int n0 = blockIdx.x * 64;
  const int cnt = counts[e];
  if (m0 >= cnt) return;
  const int pairBase = offsets[e];

  __shared__ __align__(16) unsigned short As[128 * 64];   // unpadded (global_load_lds), XOR-swizzled
  __shared__ __align__(16) unsigned short Bs[128 * 64];
  __shared__ int tokS[128];

  const int tid = threadIdx.x;
  if (tid < 128) {
    int r = m0 + tid;
    tokS[tid] = (r < cnt) ? row_token[pairBase + r] : row_token[pairBase];  // clamp: safe garbage
  }
  __syncthreads();

  const int lane = tid & 63;
  const int wave = tid >> 6;
  const int quad = lane >> 4;
  const int l16  = lane & 15;
  const int lr   = lane >> 3;          // 0..7 staging row in 8-row group
  const int lc   = lane & 7;           // 0..7 16B chunk (pre-swizzle)
  const int sw   = lc ^ (lr & 7);      // swizzled global chunk this lane fetches
  const int wr   = wave >> 1;          // row half
  const int wc   = wave & 1;           // col half

  const unsigned short* W1e = W1b + (size_t)e * TWO_F * D;
  const unsigned short* aptr[4];
  const unsigned short* bptr[4];
#pragma unroll
  for (int i = 0; i < 4; ++i) {
    int r = wave * 32 + i * 8 + lr;
    aptr[i] = xb + (size_t)tokS[r] * D + sw * 8;
    int g = r >> 5, s = r & 31;
    int wrow = (g & 1) * F + n0 + (g >> 1) * 32 + s;
    bptr[i] = W1e + (size_t)wrow * D + sw * 8;
  }
  unsigned short* AsW = As + (wave * 32) * 64;
  unsigned short* BsW = Bs + (wave * 32) * 64;

  f32x4 acc[4][4];
#pragma unroll
  for (int i = 0; i < 4; ++i)
#pragma unroll
    for (int j = 0; j < 4; ++j) acc[i][j] = (f32x4){0.f, 0.f, 0.f, 0.f};

  for (int k0 = 0; k0 < D; k0 += 64) {
#pragma unroll
    for (int i = 0; i < 4; ++i) load_lds16(aptr[i] + k0, AsW + i * 8 * 64);
#pragma unroll
    for (int i = 0; i < 4; ++i) load_lds16(bptr[i] + k0, BsW + i * 8 * 64);
    __syncthreads();
#pragma unroll
    for (int kk = 0; kk < 64; kk += 32) {
      bf16x8 af[4], bf[4];
#pragma unroll
      for (int i = 0; i < 4; ++i)
        af[i] = *frag_addr(As, wr * 64 + i * 16 + l16, kk, quad);
#pragma unroll
      for (int j = 0; j < 4; ++j)
        bf[j] = *frag_addr(Bs, wc * 64 + j * 16 + l16, kk, quad);
#pragma unroll
      for (int i = 0; i < 4; ++i)
#pragma unroll
        for (int j = 0; j < 4; ++j)
          acc[i][j] = __builtin_amdgcn_mfma_f32_16x16x32_bf16(af[i], bf[j], acc[i][j], 0, 0, 0);
    }
    __syncthreads();
  }

  // Epilogue: a = h1 * silu(h2); acc[i][j] (j=0,1 -> h1) pairs acc[i][j+2] (h2), same lane map.
#pragma unroll
  for (int i = 0; i < 4; ++i) {
    int rb = wr * 64 + i * 16 + quad * 4;
#pragma unroll
    for (int j = 0; j < 2; ++j) {
      int col = n0 + wc * 32 + j * 16 + l16;
      float bh1 = b1[e * TWO_F + col];
      float bh2 = b1[e * TWO_F + F + col];
#pragma unroll
      for (int rg = 0; rg < 4; ++rg) {
        int r = rb + rg;
        if (m0 + r < cnt) {
          float h1 = acc[i][j][rg] + bh1;
          float h2 = acc[i][j + 2][rg] + bh2;
          float a  = h1 * (h2 / (1.f + __expf(-h2)));
          a_buf[(size_t)(pairBase + m0 + r) * F + col] = f32_to_bf16(a);
        }
      }
    }
  }
}

// GEMM2: y = a @ W2[e]^T ; out[token] += gate * (y + b2)  (fp32 atomics, out pre-zeroed)
__global__ __launch_bounds__(256, 2)
void gemm2_kernel(const unsigned short* __restrict__ a_buf,
                  const unsigned short* __restrict__ W2b,
                  const float* __restrict__ b2,
                  const int* __restrict__ counts, const int* __restrict__ offsets,
                  const int* __restrict__ row_token, const float* __restrict__ row_gate,
                  float* __restrict__ out, int totalPairs) {
  const int e  = blockIdx.z;
  const int m0 = blockIdx.y * 128;
  const int n0 = blockIdx.x * 128;
  const int cnt = counts[e];
  if (m0 >= cnt) return;
  const int pairBase = offsets[e];

  __shared__ __align__(16) unsigned short As[128 * 64];
  __shared__ __align__(16) unsigned short Bs[128 * 64];
  __shared__ int   tokS[128];
  __shared__ float gateS[128];

  const int tid = threadIdx.x;
  if (tid < 128) {
    int r = m0 + tid;
    bool v = (r < cnt);
    tokS[tid]  = v ? row_token[pairBase + r] : 0;
    gateS[tid] = v ? row_gate[pairBase + r] : 0.f;
  }
  __syncthreads();

  const int lane = tid & 63;
  const int wave = tid >> 6;
  const int quad = lane >> 4;
  const int l16  = lane & 15;
  const int lr   = lane >> 3;
  const int lc   = lane & 7;
  const int sw   = lc ^ (lr & 7);
  const int wr   = wave >> 1;
  const int wc   = wave & 1;

  const unsigned short* W2e = W2b + (size_t)e * D * F;
  const unsigned short* aptr[4];
  const unsigned short* bptr[4];
#pragma unroll
  for (int i = 0; i < 4; ++i) {
    int r = wave * 32 + i * 8 + lr;
    int g = pairBase + m0 + r;
    if (g > totalPairs - 1) g = totalPairs - 1;   // clamp: stay inside a_buf
    aptr[i] = a_buf + (size_t)g * F + sw * 8;
    bptr[i] = W2e + (size_t)(n0 + r) * F + sw * 8;
  }
  unsigned short* AsW = As + (wave * 32) * 64;
  unsigned short* BsW = Bs + (wave * 32) * 64;

  f32x4 acc[4][4];
#pragma unroll
  for (int i = 0; i < 4; ++i)
#pragma unroll
    for (int j = 0; j < 4; ++j) acc[i][j] = (f32x4){0.f, 0.f, 0.f, 0.f};

  for (int k0 = 0; k0 < F; k0 += 64) {
#pragma unroll
    for (int i = 0; i < 4; ++i) load_lds16(aptr[i] + k0, AsW + i * 8 * 64);
#pragma unroll
    for (int i = 0; i < 4; ++i) load_lds16(bptr[i] + k0, BsW + i * 8 * 64);
    __syncthreads();
#pragma unroll
    for (int kk = 0; kk < 64; kk += 32) {
      bf16x8 af[4], bf[4];
#pragma unroll
      for (int i = 0; i < 4; ++i)
        af[i] = *frag_addr(As, wr * 64 + i * 16 + l16, kk, quad);
#pragma unroll
      for (int j = 0; j < 4; ++j)
        bf[j] = *frag_addr(Bs, wc * 64 + j * 16 + l16, kk, quad);
#pragma unroll
      for (int i = 0; i < 4; ++i)
#pragma unroll
        for (int j = 0; j < 4; ++j)
          acc[i][j] = __builtin_amdgcn_mfma_f32_16x16x32_bf16(af[i], bf[j], acc[i][j], 0, 0, 0);
    }
    __syncthreads();
  }

#pragma unroll
  for (int j = 0; j < 4; ++j) {
    int col = n0 + wc * 64 + j * 16 + l16;
    float b2v = b2[e * D + col];
#pragma unroll
    for (int i = 0; i < 4; ++i) {
      int rb = wr * 64 + i * 16 + quad * 4;
#pragma unroll
      for (int rg = 0; rg < 4; ++rg) {
        int r = rb + rg;
        if (m0 + r < cnt) {
          float y = (acc[i][j][rg] + b2v) * gateS[r];
          atomicAdd(&out[(size_t)tokS[r] * D + col], y);
        }
      }
    }
  }
}

}  // namespace

extern "C" void kernel_launch(void* const* d_in, const int* in_sizes, int n_in,
                              void* d_out, int out_size, void* d_ws, size_t ws_size,
                              hipStream_t stream) {
  (void)n_in; (void)out_size; (void)ws_size;
  const float* x    = (const float*)d_in[0];
  const float* Wr   = (const float*)d_in[1];
  const float* temp = (const float*)d_in[2];
  const float* W1   = (const float*)d_in[3];
  const float* b1   = (const float*)d_in[4];
  const float* W2   = (const float*)d_in[5];
  const float* b2   = (const float*)d_in[6];
  float* out = (float*)d_out;
  const int T = in_sizes[0] / D;   // 4096

  // workspace layout (~137 MB)
  char* ws = (char*)d_ws;
  size_t off = 0;
  unsigned short* xb    = (unsigned short*)(ws + off); off += (size_t)T * D * 2;
  unsigned short* W1b   = (unsigned short*)(ws + off); off += (size_t)E * TWO_F * D * 2;
  unsigned short* W2b   = (unsigned short*)(ws + off); off += (size_t)E * D * F * 2;
  unsigned short* a_buf = (unsigned short*)(ws + off); off += (size_t)T * 2 * F * 2;
  int*   counts    = (int*)(ws + off); off += 64;
  int*   offsets   = (int*)(ws + off); off += 64;
  int*   counts2   = (int*)(ws + off); off += 64;
  int*   topk_idx  = (int*)(ws + off); off += (size_t)T * 2 * 4;
  float* topk_gate = (float*)(ws + off); off += (size_t)T * 2 * 4;
  int*   row_token = (int*)(ws + off); off += (size_t)T * 2 * 4;
  float* row_gate  = (float*)(ws + off); off += (size_t)T * 2 * 4;

  const long long nx = (long long)T * D;
  const long long n1 = (long long)E * TWO_F * D;
  const long long n2 = (long long)E * D * F;

  zero_kernel<<<(T * D / 4 + 255) / 256, 256, 0, stream>>>(out, T * D / 4, counts);
  cvt_all_kernel<<<(int)((nx + n1 + n2) / 2048), 256, 0, stream>>>(x, W1, W2, xb, W1b, W2b,
                                                                   nx, n1);
  router_kernel<<<(T + 3) / 4, 256, 0, stream>>>(x, Wr, temp, topk_idx, topk_gate, counts, T);
  scan_kernel<<<1, 64, 0, stream>>>(counts, offsets);
  build_kernel<<<(T + 255) / 256, 256, 0, stream>>>(topk_idx, topk_gate, offsets, counts2,
                                                    row_token, row_gate, T);

  const int MT = (T + 127) / 128;
  gemm1_kernel<<<dim3(F / 64, MT, E), 256, 0, stream>>>(xb, W1b, b1, counts, offsets,
                                                        row_token, a_buf);
  gemm2_kernel<<<dim3(D / 128, MT, E), 256, 0, stream>>>(a_buf, W2b, b2, counts, offsets,
                                                         row_token, row_gate, out, T * 2);
}

// Round 4
// 476.635 us; speedup vs baseline: 1.4757x; 1.2336x over previous
//
#include <hip/hip_runtime.h>
#include <hip/hip_bf16.h>

#define DEV __device__ __forceinline__

namespace {

constexpr int D     = 1024;
constexpr int F     = 2048;
constexpr int E     = 8;
constexpr int TWO_F = 2 * F;

typedef short bf16x8 __attribute__((ext_vector_type(8)));
typedef float f32x4  __attribute__((ext_vector_type(4)));

DEV unsigned short f32_to_bf16(float f) {
  unsigned int u = __builtin_bit_cast(unsigned int, f);
  u += 0x7fffu + ((u >> 16) & 1u);   // RNE
  return (unsigned short)(u >> 16);
}

// async global->LDS, 16B per lane; LDS dest is wave-uniform base + lane*16 implicit
DEV void load_lds16(const void* g, void* l) {
  __builtin_amdgcn_global_load_lds((const __attribute__((address_space(1))) void*)g,
                                   (__attribute__((address_space(3))) void*)l, 16, 0, 0);
}

// XOR-swizzled fragment address: LDS[row][c] holds global chunk c ^ (row&7).
DEV const bf16x8* frag_addr(const unsigned short* S, int row, int kk, int quad) {
  int cl = (((kk >> 3) + quad) ^ (row & 7));
  return (const bf16x8*)(S + row * 64 + cl * 8);
}

__global__ void zero_kernel(float* __restrict__ p, int n4) {
  int i = blockIdx.x * 256 + threadIdx.x;
  if (i < n4) ((float4*)p)[i] = make_float4(0.f, 0.f, 0.f, 0.f);
}

// One fused fp32->bf16 conversion over x, W1, W2 (sizes are multiples of 2048 elems).
__global__ void cvt_all_kernel(const float* __restrict__ x, const float* __restrict__ W1,
                               const float* __restrict__ W2,
                               unsigned short* __restrict__ xb, unsigned short* __restrict__ W1b,
                               unsigned short* __restrict__ W2b,
                               long long nx, long long n1) {
  long long i = (long long)(blockIdx.x * 256 + threadIdx.x) * 8;
  const float* src;
  unsigned short* dst;
  long long off;
  if (i < nx)            { src = x;  dst = xb;  off = i; }
  else if (i < nx + n1)  { src = W1; dst = W1b; off = i - nx; }
  else                   { src = W2; dst = W2b; off = i - nx - n1; }
  float4 a = *(const float4*)(src + off);
  float4 b = *(const float4*)(src + off + 4);
  uint4 o;
  o.x = (unsigned)f32_to_bf16(a.x) | ((unsigned)f32_to_bf16(a.y) << 16);
  o.y = (unsigned)f32_to_bf16(a.z) | ((unsigned)f32_to_bf16(a.w) << 16);
  o.z = (unsigned)f32_to_bf16(b.x) | ((unsigned)f32_to_bf16(b.y) << 16);
  o.w = (unsigned)f32_to_bf16(b.z) | ((unsigned)f32_to_bf16(b.w) << 16);
  *(uint4*)(dst + off) = o;
}

// Router: one wave per token; fp32 dot over D=1024, top-2 + softmax. NO atomics.
__global__ void router_kernel(const float* __restrict__ x, const float* __restrict__ Wr,
                              const float* __restrict__ temp,
                              int* __restrict__ topk_idx, float* __restrict__ topk_gate, int T) {
  int wid  = blockIdx.x * 4 + (threadIdx.x >> 6);
  int lane = threadIdx.x & 63;
  if (wid >= T) return;
  const float* xr = x + (size_t)wid * D;
  float acc[E];
#pragma unroll
  for (int e = 0; e < E; ++e) acc[e] = 0.f;
  int base = lane * 16;
#pragma unroll
  for (int u = 0; u < 4; ++u) {
    float4 xv = *(const float4*)(xr + base + u * 4);
#pragma unroll
    for (int e = 0; e < E; ++e) {
      float4 wv = *(const float4*)(Wr + e * D + base + u * 4);
      acc[e] += xv.x * wv.x + xv.y * wv.y + xv.z * wv.z + xv.w * wv.w;
    }
  }
#pragma unroll
  for (int e = 0; e < E; ++e) {
    float v = acc[e];
#pragma unroll
    for (int off = 32; off > 0; off >>= 1) v += __shfl_xor(v, off, 64);
    acc[e] = v;
  }
  if (lane == 0) {
    float inv = 1.0f / temp[0];
    float l[E];
#pragma unroll
    for (int e = 0; e < E; ++e) l[e] = acc[e] * inv;
    int e0 = 0;
#pragma unroll
    for (int e = 1; e < E; ++e) if (l[e] > l[e0]) e0 = e;   // first-index tie-break like top_k
    int e1 = (e0 == 0) ? 1 : 0;
#pragma unroll
    for (int e = 0; e < E; ++e) if (e != e0 && l[e] > l[e1]) e1 = e;
    float dlt = l[e1] - l[e0];
    float ed  = __expf(dlt);
    topk_idx[2 * wid]      = e0;
    topk_idx[2 * wid + 1]  = e1;
    topk_gate[2 * wid]     = 1.f / (1.f + ed);
    topk_gate[2 * wid + 1] = ed / (1.f + ed);
  }
}

// Single block, 1024 threads: histogram (LDS atomics) -> scan -> compacted expert lists.
// Replaces global-atomic counting (8192 device atomics to one cache line was ~106 us).
__global__ __launch_bounds__(1024)
void assign_kernel(const int* __restrict__ topk_idx, const float* __restrict__ topk_gate,
                   int* __restrict__ counts, int* __restrict__ offsets,
                   int* __restrict__ row_token, float* __restrict__ row_gate, int T) {
  __shared__ int hist[E];
  __shared__ int cur[E];
  const int tid = threadIdx.x;
  if (tid < E) hist[tid] = 0;
  __syncthreads();
  for (int t = tid; t < T; t += 1024) {
    atomicAdd(&hist[topk_idx[2 * t]], 1);
    atomicAdd(&hist[topk_idx[2 * t + 1]], 1);
  }
  __syncthreads();
  if (tid == 0) {
    int s = 0;
    for (int e = 0; e < E; ++e) {
      int c = hist[e];
      counts[e]  = c;
      offsets[e] = s;
      cur[e]     = s;
      s += c;
    }
  }
  __syncthreads();
  for (int t = tid; t < T; t += 1024) {
#pragma unroll
    for (int s = 0; s < 2; ++s) {
      int e = topk_idx[2 * t + s];
      int p = atomicAdd(&cur[e], 1);
      row_token[p] = t;
      row_gate[p]  = topk_gate[2 * t + s];
    }
  }
}

// GEMM1: h = gather(x) @ W1[e]^T; fused SwiGLU -> a_buf (bf16).
// 256 thr / 2x2 waves; tile 128 tokens x 64 a-cols (128 h-cols). BK=64.
// Bs row grouping: [h1 c0..31 | h2 c0..31 | h1 c32..63 | h2 c32..63]; acc[i][j] pairs acc[i][j+2].
__global__ __launch_bounds__(256, 2)
void gemm1_kernel(const unsigned short* __restrict__ xb,
                  const unsigned short* __restrict__ W1b,
                  const float* __restrict__ b1,
                  const int* __restrict__ counts, const int* __restrict__ offsets,
                  const int* __restrict__ row_token,
                  unsigned short* __restrict__ a_buf) {
  const int e  = blockIdx.z;
  const int m0 = blockIdx.y * 128;
  const int n0 = blockIdx.x * 64;
  const int cnt = counts[e];
  if (m0 >= cnt) return;
  const int pairBase = offsets[e];

  __shared__ __align__(16) unsigned short As[128 * 64];   // unpadded (global_load_lds), XOR-swizzled
  __shared__ __align__(16) unsigned short Bs[128 * 64];
  __shared__ int tokS[128];

  const int tid = threadIdx.x;
  if (tid < 128) {
    int r = m0 + tid;
    tokS[tid] = (r < cnt) ? row_token[pairBase + r] : row_token[pairBase];  // clamp: safe garbage
  }
  __syncthreads();

  const int lane = tid & 63;
  const int wave = tid >> 6;
  const int quad = lane >> 4;
  const int l16  = lane & 15;
  const int lr   = lane >> 3;
  const int lc   = lane & 7;
  const int sw   = lc ^ (lr & 7);      // swizzled global chunk this lane fetches
  const int wr   = wave >> 1;
  const int wc   = wave & 1;

  const unsigned short* W1e = W1b + (size_t)e * TWO_F * D;
  const unsigned short* aptr[4];
  const unsigned short* bptr[4];
#pragma unroll
  for (int i = 0; i < 4; ++i) {
    int r = wave * 32 + i * 8 + lr;
    aptr[i] = xb + (size_t)tokS[r] * D + sw * 8;
    int g = r >> 5, s = r & 31;
    int wrow = (g & 1) * F + n0 + (g >> 1) * 32 + s;
    bptr[i] = W1e + (size_t)wrow * D + sw * 8;
  }
  unsigned short* AsW = As + (wave * 32) * 64;
  unsigned short* BsW = Bs + (wave * 32) * 64;

  f32x4 acc[4][4];
#pragma unroll
  for (int i = 0; i < 4; ++i)
#pragma unroll
    for (int j = 0; j < 4; ++j) acc[i][j] = (f32x4){0.f, 0.f, 0.f, 0.f};

  for (int k0 = 0; k0 < D; k0 += 64) {
#pragma unroll
    for (int i = 0; i < 4; ++i) load_lds16(aptr[i] + k0, AsW + i * 8 * 64);
#pragma unroll
    for (int i = 0; i < 4; ++i) load_lds16(bptr[i] + k0, BsW + i * 8 * 64);
    __syncthreads();
#pragma unroll
    for (int kk = 0; kk < 64; kk += 32) {
      bf16x8 af[4], bf[4];
#pragma unroll
      for (int i = 0; i < 4; ++i)
        af[i] = *frag_addr(As, wr * 64 + i * 16 + l16, kk, quad);
#pragma unroll
      for (int j = 0; j < 4; ++j)
        bf[j] = *frag_addr(Bs, wc * 64 + j * 16 + l16, kk, quad);
#pragma unroll
      for (int i = 0; i < 4; ++i)
#pragma unroll
        for (int j = 0; j < 4; ++j)
          acc[i][j] = __builtin_amdgcn_mfma_f32_16x16x32_bf16(af[i], bf[j], acc[i][j], 0, 0, 0);
    }
    __syncthreads();
  }

  // Epilogue: a = h1 * silu(h2); acc[i][j] (j=0,1 -> h1) pairs acc[i][j+2] (h2).
#pragma unroll
  for (int i = 0; i < 4; ++i) {
    int rb = wr * 64 + i * 16 + quad * 4;
#pragma unroll
    for (int j = 0; j < 2; ++j) {
      int col = n0 + wc * 32 + j * 16 + l16;
      float bh1 = b1[e * TWO_F + col];
      float bh2 = b1[e * TWO_F + F + col];
#pragma unroll
      for (int rg = 0; rg < 4; ++rg) {
        int r = rb + rg;
        if (m0 + r < cnt) {
          float h1 = acc[i][j][rg] + bh1;
          float h2 = acc[i][j + 2][rg] + bh2;
          float a  = h1 * (h2 / (1.f + __expf(-h2)));
          a_buf[(size_t)(pairBase + m0 + r) * F + col] = f32_to_bf16(a);
        }
      }
    }
  }
}

// GEMM2: y = a @ W2[e]^T ; out[token] += gate * (y + b2)  (fp32 atomics, out pre-zeroed)
__global__ __launch_bounds__(256, 2)
void gemm2_kernel(const unsigned short* __restrict__ a_buf,
                  const unsigned short* __restrict__ W2b,
                  const float* __restrict__ b2,
                  const int* __restrict__ counts, const int* __restrict__ offsets,
                  const int* __restrict__ row_token, const float* __restrict__ row_gate,
                  float* __restrict__ out, int totalPairs) {
  const int e  = blockIdx.z;
  const int m0 = blockIdx.y * 128;
  const int n0 = blockIdx.x * 128;
  const int cnt = counts[e];
  if (m0 >= cnt) return;
  const int pairBase = offsets[e];

  __shared__ __align__(16) unsigned short As[128 * 64];
  __shared__ __align__(16) unsigned short Bs[128 * 64];
  __shared__ int   tokS[128];
  __shared__ float gateS[128];

  const int tid = threadIdx.x;
  if (tid < 128) {
    int r = m0 + tid;
    bool v = (r < cnt);
    tokS[tid]  = v ? row_token[pairBase + r] : 0;
    gateS[tid] = v ? row_gate[pairBase + r] : 0.f;
  }
  __syncthreads();

  const int lane = tid & 63;
  const int wave = tid >> 6;
  const int quad = lane >> 4;
  const int l16  = lane & 15;
  const int lr   = lane >> 3;
  const int lc   = lane & 7;
  const int sw   = lc ^ (lr & 7);
  const int wr   = wave >> 1;
  const int wc   = wave & 1;

  const unsigned short* W2e = W2b + (size_t)e * D * F;
  const unsigned short* aptr[4];
  const unsigned short* bptr[4];
#pragma unroll
  for (int i = 0; i < 4; ++i) {
    int r = wave * 32 + i * 8 + lr;
    int g = pairBase + m0 + r;
    if (g > totalPairs - 1) g = totalPairs - 1;   // clamp: stay inside a_buf
    aptr[i] = a_buf + (size_t)g * F + sw * 8;
    bptr[i] = W2e + (size_t)(n0 + r) * F + sw * 8;
  }
  unsigned short* AsW = As + (wave * 32) * 64;
  unsigned short* BsW = Bs + (wave * 32) * 64;

  f32x4 acc[4][4];
#pragma unroll
  for (int i = 0; i < 4; ++i)
#pragma unroll
    for (int j = 0; j < 4; ++j) acc[i][j] = (f32x4){0.f, 0.f, 0.f, 0.f};

  for (int k0 = 0; k0 < F; k0 += 64) {
#pragma unroll
    for (int i = 0; i < 4; ++i) load_lds16(aptr[i] + k0, AsW + i * 8 * 64);
#pragma unroll
    for (int i = 0; i < 4; ++i) load_lds16(bptr[i] + k0, BsW + i * 8 * 64);
    __syncthreads();
#pragma unroll
    for (int kk = 0; kk < 64; kk += 32) {
      bf16x8 af[4], bf[4];
#pragma unroll
      for (int i = 0; i < 4; ++i)
        af[i] = *frag_addr(As, wr * 64 + i * 16 + l16, kk, quad);
#pragma unroll
      for (int j = 0; j < 4; ++j)
        bf[j] = *frag_addr(Bs, wc * 64 + j * 16 + l16, kk, quad);
#pragma unroll
      for (int i = 0; i < 4; ++i)
#pragma unroll
        for (int j = 0; j < 4; ++j)
          acc[i][j] = __builtin_amdgcn_mfma_f32_16x16x32_bf16(af[i], bf[j], acc[i][j], 0, 0, 0);
    }
    __syncthreads();
  }

#pragma unroll
  for (int j = 0; j < 4; ++j) {
    int col = n0 + wc * 64 + j * 16 + l16;
    float b2v = b2[e * D + col];
#pragma unroll
    for (int i = 0; i < 4; ++i) {
      int rb = wr * 64 + i * 16 + quad * 4;
#pragma unroll
      for (int rg = 0; rg < 4; ++rg) {
        int r = rb + rg;
        if (m0 + r < cnt) {
          float y = (acc[i][j][rg] + b2v) * gateS[r];
          atomicAdd(&out[(size_t)tokS[r] * D + col], y);
        }
      }
    }
  }
}

}  // namespace

extern "C" void kernel_launch(void* const* d_in, const int* in_sizes, int n_in,
                              void* d_out, int out_size, void* d_ws, size_t ws_size,
                              hipStream_t stream) {
  (void)n_in; (void)out_size; (void)ws_size;
  const float* x    = (const float*)d_in[0];
  const float* Wr   = (const float*)d_in[1];
  const float* temp = (const float*)d_in[2];
  const float* W1   = (const float*)d_in[3];
  const float* b1   = (const float*)d_in[4];
  const float* W2   = (const float*)d_in[5];
  const float* b2   = (const float*)d_in[6];
  float* out = (float*)d_out;
  const int T = in_sizes[0] / D;   // 4096

  // workspace layout (~137 MB)
  char* ws = (char*)d_ws;
  size_t off = 0;
  unsigned short* xb    = (unsigned short*)(ws + off); off += (size_t)T * D * 2;
  unsigned short* W1b   = (unsigned short*)(ws + off); off += (size_t)E * TWO_F * D * 2;
  unsigned short* W2b   = (unsigned short*)(ws + off); off += (size_t)E * D * F * 2;
  unsigned short* a_buf = (unsigned short*)(ws + off); off += (size_t)T * 2 * F * 2;
  int*   counts    = (int*)(ws + off); off += 64;
  int*   offsets   = (int*)(ws + off); off += 64;
  int*   topk_idx  = (int*)(ws + off); off += (size_t)T * 2 * 4;
  float* topk_gate = (float*)(ws + off); off += (size_t)T * 2 * 4;
  int*   row_token = (int*)(ws + off); off += (size_t)T * 2 * 4;
  float* row_gate  = (float*)(ws + off); off += (size_t)T * 2 * 4;

  const long long nx = (long long)T * D;
  const long long n1 = (long long)E * TWO_F * D;
  const long long n2 = (long long)E * D * F;

  zero_kernel<<<(T * D / 4 + 255) / 256, 256, 0, stream>>>(out, T * D / 4);
  router_kernel<<<(T + 3) / 4, 256, 0, stream>>>(x, Wr, temp, topk_idx, topk_gate, T);
  assign_kernel<<<1, 1024, 0, stream>>>(topk_idx, topk_gate, counts, offsets,
                                        row_token, row_gate, T);
  cvt_all_kernel<<<(int)((nx + n1 + n2) / 2048), 256, 0, stream>>>(x, W1, W2, xb, W1b, W2b,
                                                                   nx, n1);
  gemm1_kernel<<<dim3(F / 64, (T * 2 + 127) / 128, E), 256, 0, stream>>>(xb, W1b, b1, counts,
                                                                         offsets, row_token, a_buf);
  gemm2_kernel<<<dim3(D / 128, (T * 2 + 127) / 128, E), 256, 0, stream>>>(a_buf, W2b, b2, counts,
                                                                          offsets, row_token,
                                                                          row_gate, out, T * 2);
}